// Round 1
// baseline (224.815 us; speedup 1.0000x reference)
//
#include <hip/hip_runtime.h>

#define ALG_DIM 248
#define ROWS 32                    // rows per main-kernel block
#define KSPLIT 2
#define KPB (ALG_DIM / KSPLIT)     // 124 k-buckets per block
#define NSTREAMS 32                // 256 threads / 8 quad-lanes

// ---------- prep: bucket triples by idx_k (ws re-poisoned every launch) ----------

__global__ void k_zero(int* __restrict__ cnt) {
    int t = threadIdx.x;
    if (t < ALG_DIM) cnt[t] = 0;
}

__global__ void k_count(const int* __restrict__ idx_k, int* __restrict__ cnt, int nnz) {
    int t = blockIdx.x * blockDim.x + threadIdx.x;
    if (t < nnz) atomicAdd(&cnt[idx_k[t]], 1);
}

__global__ void k_scan(const int* __restrict__ cnt, int* __restrict__ offs,
                       int* __restrict__ cursor) {
    __shared__ int buf[256];
    int t = threadIdx.x;
    int v = (t < ALG_DIM) ? cnt[t] : 0;
    buf[t] = v;
    __syncthreads();
    // Hillis-Steele inclusive scan over 256 entries
    for (int off = 1; off < 256; off <<= 1) {
        int add = (t >= off) ? buf[t - off] : 0;
        __syncthreads();
        buf[t] += add;
        __syncthreads();
    }
    if (t < ALG_DIM) {
        int ex = buf[t] - v;       // exclusive prefix
        offs[t]   = ex;
        cursor[t] = ex;
    }
    if (t == ALG_DIM - 1) offs[ALG_DIM] = buf[t];
}

__global__ void k_scatter(const int* __restrict__ idx_i, const int* __restrict__ idx_j,
                          const int* __restrict__ idx_k, const float* __restrict__ coeff,
                          int* __restrict__ cursor, uint2* __restrict__ packed, int nnz) {
    int t = blockIdx.x * blockDim.x + threadIdx.x;
    if (t < nnz) {
        int k = idx_k[t];
        int pos = atomicAdd(&cursor[k], 1);
        uint2 p;
        p.x = (unsigned)idx_i[t] | ((unsigned)idx_j[t] << 16);
        p.y = __float_as_uint(coeff[t]);
        packed[pos] = p;
    }
}

// ---------- main: bucketed gather-multiply-accumulate, no atomics ----------
// Block: 256 threads = 32 streams x 8 row-quads. Each stream owns ~4 whole
// k-buckets, accumulates out[4 rows][k] in registers. x,y staged in LDS
// column-major [248][32] so a lane's 4-row gather is one ds_read_b128.

__global__ __launch_bounds__(256, 2) void k_main(
    const float* __restrict__ x, const float* __restrict__ y,
    const int* __restrict__ offs, const uint2* __restrict__ packed,
    const float* __restrict__ alpha_p, float* __restrict__ out)
{
    __shared__ __align__(16) float xs[ALG_DIM * ROWS];
    __shared__ __align__(16) float ys[ALG_DIM * ROWS];

    const int tid = threadIdx.x;
    const int r0  = blockIdx.x * ROWS;
    const int kbase = blockIdx.y * KPB;

    // Stage x,y -> LDS column-major: xs[i*32 + r]. Consecutive u -> consecutive
    // LDS addresses (conflict-free stores); global reads stride-248 per lane but
    // the 32-row x 64B-line working set lives in L1 across the i-sweep.
    for (int u = tid; u < ALG_DIM * ROWS; u += 256) {
        int i = u >> 5;
        int r = u & 31;
        xs[u] = x[(size_t)(r0 + r) * ALG_DIM + i];
        ys[u] = y[(size_t)(r0 + r) * ALG_DIM + i];
    }
    __syncthreads();

    const float alpha = alpha_p[0];
    const int S = tid >> 3;       // stream id 0..31
    const int q = tid & 7;        // row-quad 0..7 (rows 4q..4q+3)

    for (int koff = S; koff < KPB; koff += NSTREAMS) {
        const int k  = kbase + koff;
        const int ts = offs[k];
        const int te = offs[k + 1];

        float4 acc = make_float4(0.f, 0.f, 0.f, 0.f);
        uint2 p;
        if (ts < te) p = packed[ts];

        for (int t = ts; t < te; ++t) {
            uint2 cur = p;
            if (t + 1 < te) p = packed[t + 1];   // prefetch next triple
            const int   i = cur.x & 0xFFFF;
            const int   j = cur.x >> 16;
            const float c = __uint_as_float(cur.y);
            const float4 xv = *reinterpret_cast<const float4*>(&xs[(i << 5) + (q << 2)]);
            const float4 yv = *reinterpret_cast<const float4*>(&ys[(j << 5) + (q << 2)]);
            acc.x += xv.x * yv.x * c;
            acc.y += xv.y * yv.y * c;
            acc.z += xv.z * yv.z * c;
            acc.w += xv.w * yv.w * c;
        }

        const int rbase = r0 + (q << 2);
        out[(size_t)(rbase + 0) * ALG_DIM + k] = alpha * acc.x;
        out[(size_t)(rbase + 1) * ALG_DIM + k] = alpha * acc.y;
        out[(size_t)(rbase + 2) * ALG_DIM + k] = alpha * acc.z;
        out[(size_t)(rbase + 3) * ALG_DIM + k] = alpha * acc.w;
    }
}

// ---------- launch ----------

extern "C" void kernel_launch(void* const* d_in, const int* in_sizes, int n_in,
                              void* d_out, int out_size, void* d_ws, size_t ws_size,
                              hipStream_t stream) {
    const float* x      = (const float*)d_in[0];
    const float* y      = (const float*)d_in[1];
    const int*   idx_i  = (const int*)d_in[2];
    const int*   idx_j  = (const int*)d_in[3];
    const int*   idx_k  = (const int*)d_in[4];
    const float* coeff  = (const float*)d_in[5];
    const float* alpha  = (const float*)d_in[6];
    float*       out    = (float*)d_out;

    const int nnz   = in_sizes[2];
    const int batch = in_sizes[0] / ALG_DIM;

    // workspace layout: [cnt 256][offs 256][cursor 256][packed nnz*uint2]
    char*  ws     = (char*)d_ws;
    int*   cnt    = (int*)ws;
    int*   offs   = cnt + 256;
    int*   cursor = offs + 256;
    uint2* packed = (uint2*)(ws + 3 * 256 * sizeof(int));

    k_zero<<<1, 256, 0, stream>>>(cnt);
    k_count<<<(nnz + 255) / 256, 256, 0, stream>>>(idx_k, cnt, nnz);
    k_scan<<<1, 256, 0, stream>>>(cnt, offs, cursor);
    k_scatter<<<(nnz + 255) / 256, 256, 0, stream>>>(idx_i, idx_j, idx_k, coeff,
                                                     cursor, packed, nnz);

    dim3 grid(batch / ROWS, KSPLIT);
    k_main<<<grid, 256, 0, stream>>>(x, y, offs, packed, alpha, out);
}